// Round 12
// baseline (62.892 us; speedup 1.0000x reference)
//
#include <hip/hip_runtime.h>
#include <hip/hip_bf16.h>

// CosSim2D: inputs (32,64,64,64) f32, w (1,576,128) f32, p (128), q (1)
// out (32,64,64,128) f32.
// R12 = R9 shell (2-row blocks, 1024 grid, frag-contiguous B, fused fp32
// norm, barrier-free scalar epilogue) + 4Mx1N wave grid: every wave covers
// all 128 n, so the 4 waves issue IDENTICAL B addresses -> 1 L2 pull + 3 L1
// hits per step. acc[2][8]; 8-reg named B prefetch; resync barrier /6 steps.

typedef short bf16x8 __attribute__((ext_vector_type(8)));
typedef float f32x4 __attribute__((ext_vector_type(4)));

__device__ __forceinline__ unsigned short f2bf(float f) {
    union { float f; unsigned int u; } v; v.f = f;
    unsigned int u = v.u;
    unsigned int r = (u + 0x7fffu + ((u >> 16) & 1u)) >> 16;  // RNE
    return (unsigned short)r;
}

// ---- pre-kernel: normalize w columns (fp32), store bf16 fragment-contiguous:
// wn2[((tap*2 + kc)*128 + n)*32 + koff] = w_hat[k = tap*64 + kc*32 + koff][n]
__global__ void prep_w_kernel(const float* __restrict__ w,
                              unsigned short* __restrict__ wn2) {
    const int n = blockIdx.x;
    const int lane = threadIdx.x;
    float vals[9];
    float s = 0.f;
#pragma unroll
    for (int i = 0; i < 9; ++i) {
        float v = w[(i * 64 + lane) * 128 + n];
        vals[i] = v;
        s += v * v;
    }
#pragma unroll
    for (int off = 1; off < 64; off <<= 1) s += __shfl_xor(s, off);
    const float inv = 1.0f / sqrtf(fmaxf(s, 1e-12f));
    const int kc = lane >> 5, koff = lane & 31;
#pragma unroll
    for (int i = 0; i < 9; ++i)
        wn2[((i * 2 + kc) * 128 + n) * 32 + koff] = f2bf(vals[i] * inv);
}

// ---- main: one block = (image b, output rows y0,y0+1); 128 pixels x 128 n
__global__ __launch_bounds__(256, 4) void cossim_main(
    const float* __restrict__ in, const unsigned short* __restrict__ wn,
    const float* __restrict__ p, const float* __restrict__ q,
    float* __restrict__ out) {
    // A: [4 rows][66 cols (zero-pad 0,65)][72 ch (64 + 16B pad)] bf16 = 38016 B
    __shared__ unsigned short A[4 * 66 * 72];
    __shared__ float rcsum[256];   // per-(row,col) fp32 square-sums
    __shared__ float xni[128];     // per-pixel 1/(||x||+q_eff)
    __shared__ float pfs[128];     // exp(p/P_SCALE)

    const int tid = (int)threadIdx.x;
    // bijective XCD swizzle: 1024 blocks, 8 XCDs, 128 consecutive l per XCD
    const int l = ((int)blockIdx.x & 7) * 128 + ((int)blockIdx.x >> 3);
    const int b = l >> 5, y0 = (l & 31) * 2;

    if (tid < 128) pfs[tid] = expf(p[tid] * 0.2f);

    // ---- stage 4 input rows (y0-1 .. y0+2) + fused fp32 norm partials
    {
        const int r = tid >> 6;        // staged row 0..3
        const int col = tid & 63;
        const int row = y0 + r - 1;
        unsigned short* dst = &A[(r * 66 + col + 1) * 72];
        float s = 0.f;
        if ((unsigned)row < 64u) {
            const float4* src = reinterpret_cast<const float4*>(
                in + (size_t)b * 262144 + row * 4096 + col * 64);
#pragma unroll
            for (int it = 0; it < 8; ++it) {
                float4 v0 = src[2 * it];
                float4 v1 = src[2 * it + 1];
                s += v0.x * v0.x + v0.y * v0.y + v0.z * v0.z + v0.w * v0.w;
                s += v1.x * v1.x + v1.y * v1.y + v1.z * v1.z + v1.w * v1.w;
                union { float f; unsigned u; } ux, uy, uz, uw;
                uint4 pk;
                ux.f = v0.x; uy.f = v0.y; uz.f = v0.z; uw.f = v0.w;
                pk.x = __builtin_amdgcn_perm(uy.u + 0x8000u, ux.u + 0x8000u, 0x07060302u);
                pk.y = __builtin_amdgcn_perm(uw.u + 0x8000u, uz.u + 0x8000u, 0x07060302u);
                ux.f = v1.x; uy.f = v1.y; uz.f = v1.z; uw.f = v1.w;
                pk.z = __builtin_amdgcn_perm(uy.u + 0x8000u, ux.u + 0x8000u, 0x07060302u);
                pk.w = __builtin_amdgcn_perm(uw.u + 0x8000u, uz.u + 0x8000u, 0x07060302u);
                *reinterpret_cast<uint4*>(dst + it * 8) = pk;
            }
        } else {
            uint4 z; z.x = z.y = z.z = z.w = 0u;
#pragma unroll
            for (int it = 0; it < 8; ++it)
                *reinterpret_cast<uint4*>(dst + it * 8) = z;
        }
        rcsum[tid] = s;
    }
    if (tid < 64) {  // zero border cols 0 and 65, all 4 rows
        const int r = tid >> 4, side = (tid >> 3) & 1, ch = (tid & 7) * 8;
        uint4 z; z.x = z.y = z.z = z.w = 0u;
        *reinterpret_cast<uint4*>(&A[(r * 66 + side * 65) * 72 + ch]) = z;
    }
    __syncthreads();

    // ---- per-pixel 1/(||x||+q_eff) from fp32 partials
    if (tid < 128) {
        const int ry = tid >> 6, x = tid & 63;
        const float qe = expf(q[0] * (-1.0f / 0.3f));
        float s = 0.f;
#pragma unroll
        for (int dy = 0; dy < 3; ++dy) {
            const float* rs = &rcsum[(ry + dy) * 64];
            if (x > 0) s += rs[x - 1];
            s += rs[x];
            if (x < 63) s += rs[x + 1];
        }
        xni[tid] = 1.0f / (sqrtf(fmaxf(s, 1e-12f)) + qe);
    }
    __syncthreads();   // xni/pfs ready -> epilogue needs NO barrier

    // ---- MFMA loop: wave grid 4M x 1N; wave wv owns 32 px x ALL 128 n.
    // All 4 waves read the same B fragment addresses each step.
    const int wv = tid >> 6, lane = tid & 63;
    const int lr = lane & 15, lg = lane >> 4;
    const int srow = wv >> 1;            // row-in-tile 0..1
    const int scol = (wv & 1) * 32;      // px-col base 0 or 32
    f32x4 acc[2][8] = {};
    const unsigned short* wB = wn + lr * 32 + lg * 8;

    bf16x8 bc0 = *reinterpret_cast<const bf16x8*>(wB);
    bf16x8 bc1 = *reinterpret_cast<const bf16x8*>(wB + 512);
    bf16x8 bc2 = *reinterpret_cast<const bf16x8*>(wB + 1024);
    bf16x8 bc3 = *reinterpret_cast<const bf16x8*>(wB + 1536);
    bf16x8 bc4 = *reinterpret_cast<const bf16x8*>(wB + 2048);
    bf16x8 bc5 = *reinterpret_cast<const bf16x8*>(wB + 2560);
    bf16x8 bc6 = *reinterpret_cast<const bf16x8*>(wB + 3072);
    bf16x8 bc7 = *reinterpret_cast<const bf16x8*>(wB + 3584);

#pragma unroll
    for (int s = 0; s < 18; ++s) {
        bf16x8 bn0, bn1, bn2, bn3, bn4, bn5, bn6, bn7;
        if (s + 1 < 18) {
            const unsigned short* wt = wB + (s + 1) * 4096;
            bn0 = *reinterpret_cast<const bf16x8*>(wt);
            bn1 = *reinterpret_cast<const bf16x8*>(wt + 512);
            bn2 = *reinterpret_cast<const bf16x8*>(wt + 1024);
            bn3 = *reinterpret_cast<const bf16x8*>(wt + 1536);
            bn4 = *reinterpret_cast<const bf16x8*>(wt + 2048);
            bn5 = *reinterpret_cast<const bf16x8*>(wt + 2560);
            bn6 = *reinterpret_cast<const bf16x8*>(wt + 3072);
            bn7 = *reinterpret_cast<const bf16x8*>(wt + 3584);
        }
        const int dy = s / 6, dx = (s >> 1) % 3, kc = s & 1;
#pragma unroll
        for (int mf = 0; mf < 2; ++mf) {
            const unsigned short* ap =
                &A[((srow + dy) * 66 + scol + mf * 16 + lr + dx) * 72
                   + kc * 32 + lg * 8];
            bf16x8 av = *reinterpret_cast<const bf16x8*>(ap);
            acc[mf][0] = __builtin_amdgcn_mfma_f32_16x16x32_bf16(av, bc0, acc[mf][0], 0, 0, 0);
            acc[mf][1] = __builtin_amdgcn_mfma_f32_16x16x32_bf16(av, bc1, acc[mf][1], 0, 0, 0);
            acc[mf][2] = __builtin_amdgcn_mfma_f32_16x16x32_bf16(av, bc2, acc[mf][2], 0, 0, 0);
            acc[mf][3] = __builtin_amdgcn_mfma_f32_16x16x32_bf16(av, bc3, acc[mf][3], 0, 0, 0);
            acc[mf][4] = __builtin_amdgcn_mfma_f32_16x16x32_bf16(av, bc4, acc[mf][4], 0, 0, 0);
            acc[mf][5] = __builtin_amdgcn_mfma_f32_16x16x32_bf16(av, bc5, acc[mf][5], 0, 0, 0);
            acc[mf][6] = __builtin_amdgcn_mfma_f32_16x16x32_bf16(av, bc6, acc[mf][6], 0, 0, 0);
            acc[mf][7] = __builtin_amdgcn_mfma_f32_16x16x32_bf16(av, bc7, acc[mf][7], 0, 0, 0);
        }
        bc0 = bn0; bc1 = bn1; bc2 = bn2; bc3 = bn3;
        bc4 = bn4; bc5 = bn5; bc6 = bn6; bc7 = bn7;
        if (s == 5 || s == 11) __syncthreads();  // bound wave drift: keep the
                                                 // shared B window L1-resident
    }

    // ---- epilogue (barrier-free): sim = acc*xni; out = sign*(|sim|+eps)^p
    float* orow = out + ((size_t)(b * 64 + y0 + srow) * 64) * 128;
#pragma unroll
    for (int mf = 0; mf < 2; ++mf) {
#pragma unroll
        for (int i = 0; i < 4; ++i) {
            const int px = scol + mf * 16 + lg * 4 + i;   // 0..63 in row
            const float xn = xni[srow * 64 + px];
#pragma unroll
            for (int nf = 0; nf < 8; ++nf) {
                const int n = nf * 16 + lr;
                float sim = acc[mf][nf][i] * xn;
                float aa = fabsf(sim) + 1e-6f;
                float r = exp2f(pfs[n] * log2f(aa));
                orow[(size_t)px * 128 + n] = copysignf(r, sim);
            }
        }
    }
}

extern "C" void kernel_launch(void* const* d_in, const int* in_sizes, int n_in,
                              void* d_out, int out_size, void* d_ws, size_t ws_size,
                              hipStream_t stream) {
    (void)in_sizes; (void)n_in; (void)out_size; (void)ws_size;
    const float* in = (const float*)d_in[0];
    const float* w  = (const float*)d_in[1];
    const float* p  = (const float*)d_in[2];
    const float* q  = (const float*)d_in[3];
    float* out = (float*)d_out;
    unsigned short* wn = (unsigned short*)d_ws;  // 18*128*32 bf16 = 147456 B

    prep_w_kernel<<<128, 64, 0, stream>>>(w, wn);
    cossim_main<<<1024, 256, 0, stream>>>(in, wn, p, q, out);
}

// Round 13
// 50.541 us; speedup vs baseline: 1.2444x; 1.2444x over previous
//
#include <hip/hip_runtime.h>
#include <hip/hip_bf16.h>

// CosSim2D: inputs (32,64,64,64) f32, w (1,576,128) f32, p (128), q (1)
// out (32,64,64,128) f32.
// R13: 2-row x 64px x 64n blocks (n-split), grid 2048 = 2 rounds at 4/CU ->
// true turnover (round-2 stage/compute overlaps round-1 store drain).
// Wave = 64px x 32n (acc[4][2], B:MFMA 1:4 as R9). Epilogue via LDS (reused
// A space) -> px-major float4 full-line stores (R8-proven clean under
// turnover). No mid-loop barriers. Twin n-halves l-adjacent -> same XCD.

typedef short bf16x8 __attribute__((ext_vector_type(8)));
typedef float f32x4 __attribute__((ext_vector_type(4)));

__device__ __forceinline__ unsigned short f2bf(float f) {
    union { float f; unsigned int u; } v; v.f = f;
    unsigned int u = v.u;
    unsigned int r = (u + 0x7fffu + ((u >> 16) & 1u)) >> 16;  // RNE
    return (unsigned short)r;
}

// ---- pre-kernel: normalize w columns (fp32), store bf16 fragment-contiguous:
// wn2[((tap*2 + kc)*128 + n)*32 + koff] = w_hat[k = tap*64 + kc*32 + koff][n]
__global__ void prep_w_kernel(const float* __restrict__ w,
                              unsigned short* __restrict__ wn2) {
    const int n = blockIdx.x;
    const int lane = threadIdx.x;
    float vals[9];
    float s = 0.f;
#pragma unroll
    for (int i = 0; i < 9; ++i) {
        float v = w[(i * 64 + lane) * 128 + n];
        vals[i] = v;
        s += v * v;
    }
#pragma unroll
    for (int off = 1; off < 64; off <<= 1) s += __shfl_xor(s, off);
    const float inv = 1.0f / sqrtf(fmaxf(s, 1e-12f));
    const int kc = lane >> 5, koff = lane & 31;
#pragma unroll
    for (int i = 0; i < 9; ++i)
        wn2[((i * 2 + kc) * 128 + n) * 32 + koff] = f2bf(vals[i] * inv);
}

#define OBLD 68   // OB row stride in floats

// ---- main: block = (image b, rows y0..y0+1, n-half nh); 128 px x 64 n
__global__ __launch_bounds__(256, 4) void cossim_main(
    const float* __restrict__ in, const unsigned short* __restrict__ wn,
    const float* __restrict__ p, const float* __restrict__ q,
    float* __restrict__ out) {
    // A: [4 rows][66 cols (zero-pad 0,65)][72 ch] bf16 = 38016 B;
    // reused after MFMA as OB[128 px][68] f32 (34816 B) for store transpose.
    __shared__ __align__(16) unsigned char smemRaw[4 * 66 * 72 * 2];
    unsigned short* A = reinterpret_cast<unsigned short*>(smemRaw);
    float* OB = reinterpret_cast<float*>(smemRaw);
    __shared__ float rcsum[256];   // per-(row,col) fp32 square-sums
    __shared__ float xni[128];     // per-pixel 1/(||x||+q_eff)
    __shared__ float pfs[64];      // exp(p/P_SCALE) for this n-half

    const int tid = (int)threadIdx.x;
    // bijective XCD swizzle: 2048 blocks, 8 XCDs, 256 consecutive l per XCD.
    // nh toggles fastest -> twin n-half blocks adjacent on the same XCD.
    const int l = ((int)blockIdx.x & 7) * 256 + ((int)blockIdx.x >> 3);
    const int sp = l >> 1, nh = l & 1;
    const int b = sp >> 5, y0 = (sp & 31) * 2;

    if (tid < 64) pfs[tid] = expf(p[nh * 64 + tid] * 0.2f);

    // ---- stage 4 input rows (y0-1 .. y0+2) + fused fp32 norm partials
    {
        const int r = tid >> 6;        // staged row 0..3
        const int col = tid & 63;
        const int row = y0 + r - 1;
        unsigned short* dst = &A[(r * 66 + col + 1) * 72];
        float s = 0.f;
        if ((unsigned)row < 64u) {
            const float4* src = reinterpret_cast<const float4*>(
                in + (size_t)b * 262144 + row * 4096 + col * 64);
#pragma unroll
            for (int it = 0; it < 8; ++it) {
                float4 v0 = src[2 * it];
                float4 v1 = src[2 * it + 1];
                s += v0.x * v0.x + v0.y * v0.y + v0.z * v0.z + v0.w * v0.w;
                s += v1.x * v1.x + v1.y * v1.y + v1.z * v1.z + v1.w * v1.w;
                union { float f; unsigned u; } ux, uy, uz, uw;
                uint4 pk;
                ux.f = v0.x; uy.f = v0.y; uz.f = v0.z; uw.f = v0.w;
                pk.x = __builtin_amdgcn_perm(uy.u + 0x8000u, ux.u + 0x8000u, 0x07060302u);
                pk.y = __builtin_amdgcn_perm(uw.u + 0x8000u, uz.u + 0x8000u, 0x07060302u);
                ux.f = v1.x; uy.f = v1.y; uz.f = v1.z; uw.f = v1.w;
                pk.z = __builtin_amdgcn_perm(uy.u + 0x8000u, ux.u + 0x8000u, 0x07060302u);
                pk.w = __builtin_amdgcn_perm(uw.u + 0x8000u, uz.u + 0x8000u, 0x07060302u);
                *reinterpret_cast<uint4*>(dst + it * 8) = pk;
            }
        } else {
            uint4 z; z.x = z.y = z.z = z.w = 0u;
#pragma unroll
            for (int it = 0; it < 8; ++it)
                *reinterpret_cast<uint4*>(dst + it * 8) = z;
        }
        rcsum[tid] = s;
    }
    if (tid < 64) {  // zero border cols 0 and 65, all 4 rows
        const int r = tid >> 4, side = (tid >> 3) & 1, ch = (tid & 7) * 8;
        uint4 z; z.x = z.y = z.z = z.w = 0u;
        *reinterpret_cast<uint4*>(&A[(r * 66 + side * 65) * 72 + ch]) = z;
    }
    __syncthreads();

    // ---- per-pixel 1/(||x||+q_eff) from fp32 partials
    if (tid < 128) {
        const int ry = tid >> 6, x = tid & 63;
        const float qe = expf(q[0] * (-1.0f / 0.3f));
        float s = 0.f;
#pragma unroll
        for (int dy = 0; dy < 3; ++dy) {
            const float* rs = &rcsum[(ry + dy) * 64];
            if (x > 0) s += rs[x - 1];
            s += rs[x];
            if (x < 63) s += rs[x + 1];
        }
        xni[tid] = 1.0f / (sqrtf(fmaxf(s, 1e-12f)) + qe);
    }
    __syncthreads();   // xni/pfs ready

    // ---- MFMA loop: wave = 64 px (row wm) x 32 n (quarter wq); acc[4][2]
    const int wv = tid >> 6, lane = tid & 63;
    const int lr = lane & 15, lg = lane >> 4;
    const int wm = wv >> 1, wq = wv & 1;
    f32x4 acc[4][2] = {};
    const unsigned short* wB = wn + (nh * 64 + wq * 32 + lr) * 32 + lg * 8;

    bf16x8 bc0 = *reinterpret_cast<const bf16x8*>(wB);
    bf16x8 bc1 = *reinterpret_cast<const bf16x8*>(wB + 512);

#pragma unroll
    for (int s = 0; s < 18; ++s) {
        bf16x8 bn0, bn1;
        if (s + 1 < 18) {
            const unsigned short* wt = wB + (s + 1) * 4096;
            bn0 = *reinterpret_cast<const bf16x8*>(wt);
            bn1 = *reinterpret_cast<const bf16x8*>(wt + 512);
        }
        const int dy = s / 6, dx = (s >> 1) % 3, kc = s & 1;
#pragma unroll
        for (int mf = 0; mf < 4; ++mf) {
            const unsigned short* ap =
                &A[((wm + dy) * 66 + mf * 16 + lr + dx) * 72 + kc * 32 + lg * 8];
            bf16x8 av = *reinterpret_cast<const bf16x8*>(ap);
            acc[mf][0] = __builtin_amdgcn_mfma_f32_16x16x32_bf16(av, bc0, acc[mf][0], 0, 0, 0);
            acc[mf][1] = __builtin_amdgcn_mfma_f32_16x16x32_bf16(av, bc1, acc[mf][1], 0, 0, 0);
        }
        bc0 = bn0; bc1 = bn1;
    }
    __syncthreads();   // all A-reads done -> A space reusable as OB

    // ---- epilogue: all 4 waves write OB in parallel, then float4 copy-out
    const float* pf = pfs;
#pragma unroll
    for (int mf = 0; mf < 4; ++mf) {
#pragma unroll
        for (int i = 0; i < 4; ++i) {
            const int pix = wm * 64 + mf * 16 + lg * 4 + i;   // 0..127
            const float xn = xni[pix];
#pragma unroll
            for (int nf = 0; nf < 2; ++nf) {
                const int nl = wq * 32 + nf * 16 + lr;        // 0..63
                float sim = acc[mf][nf][i] * xn;
                float aa = fabsf(sim) + 1e-6f;
                float r = exp2f(pf[nl] * log2f(aa));
                OB[pix * OBLD + nl] = copysignf(r, sim);
            }
        }
    }
    __syncthreads();   // OB ready

    // copy out: 128 px x 64 n = 2048 float4 / 256 thr = 8 each.
    // Wave instruction: 16 px x 16 consecutive n-floats -> complete 128B lines.
#pragma unroll
    for (int j = 0; j < 8; ++j) {
        const int f = tid + 256 * j;      // 0..2047
        const int px = f >> 4, c = f & 15;
        float4 v = *reinterpret_cast<const float4*>(&OB[px * OBLD + c * 4]);
        const int row = y0 + (px >> 6), col = px & 63;
        *reinterpret_cast<float4*>(
            out + ((size_t)((b * 64 + row) * 64 + col)) * 128 + nh * 64 + c * 4) = v;
    }
}

extern "C" void kernel_launch(void* const* d_in, const int* in_sizes, int n_in,
                              void* d_out, int out_size, void* d_ws, size_t ws_size,
                              hipStream_t stream) {
    (void)in_sizes; (void)n_in; (void)out_size; (void)ws_size;
    const float* in = (const float*)d_in[0];
    const float* w  = (const float*)d_in[1];
    const float* p  = (const float*)d_in[2];
    const float* q  = (const float*)d_in[3];
    float* out = (float*)d_out;
    unsigned short* wn = (unsigned short*)d_ws;  // 18*128*32 bf16 = 147456 B

    prep_w_kernel<<<128, 64, 0, stream>>>(w, wn);
    cossim_main<<<2048, 256, 0, stream>>>(in, wn, p, q, out);
}

// Round 14
// 44.238 us; speedup vs baseline: 1.4217x; 1.1425x over previous
//
#include <hip/hip_runtime.h>
#include <hip/hip_bf16.h>

// CosSim2D: inputs (32,64,64,64) f32, w (1,576,128) f32, p (128), q (1)
// out (32,64,64,128) f32.
// R14 = R9 shell (2-row blocks, 1024 grid, frag-contiguous B, fused fp32
// norm, barrier-free scalar epilogue, 128-reg envelope = 16 waves/CU)
// with MFMA shape 32x32x16 (4060 FLOP/cyc vs 3378, half the MFMA issue
// slots, same loads, same 64-AGPR acc as 2x2 f32x16 tiles).

typedef short bf16x8 __attribute__((ext_vector_type(8)));
typedef float f32x16 __attribute__((ext_vector_type(16)));

__device__ __forceinline__ unsigned short f2bf(float f) {
    union { float f; unsigned int u; } v; v.f = f;
    unsigned int u = v.u;
    unsigned int r = (u + 0x7fffu + ((u >> 16) & 1u)) >> 16;  // RNE
    return (unsigned short)r;
}

// ---- pre-kernel: normalize w columns (fp32), store bf16 fragment-contiguous:
// wn2[((tap*2 + kc)*128 + n)*32 + koff] = w_hat[k = tap*64 + kc*32 + koff][n]
__global__ void prep_w_kernel(const float* __restrict__ w,
                              unsigned short* __restrict__ wn2) {
    const int n = blockIdx.x;
    const int lane = threadIdx.x;
    float vals[9];
    float s = 0.f;
#pragma unroll
    for (int i = 0; i < 9; ++i) {
        float v = w[(i * 64 + lane) * 128 + n];
        vals[i] = v;
        s += v * v;
    }
#pragma unroll
    for (int off = 1; off < 64; off <<= 1) s += __shfl_xor(s, off);
    const float inv = 1.0f / sqrtf(fmaxf(s, 1e-12f));
    const int kc = lane >> 5, koff = lane & 31;
#pragma unroll
    for (int i = 0; i < 9; ++i)
        wn2[((i * 2 + kc) * 128 + n) * 32 + koff] = f2bf(vals[i] * inv);
}

// ---- main: one block = (image b, output rows y0,y0+1); 128 pixels x 128 n
__global__ __launch_bounds__(256, 4) void cossim_main(
    const float* __restrict__ in, const unsigned short* __restrict__ wn,
    const float* __restrict__ p, const float* __restrict__ q,
    float* __restrict__ out) {
    // A: [4 rows][66 cols (zero-pad 0,65)][72 ch (64 + 16B pad)] bf16 = 38016 B
    __shared__ unsigned short A[4 * 66 * 72];
    __shared__ float rcsum[256];   // per-(row,col) fp32 square-sums
    __shared__ float xni[128];     // per-pixel 1/(||x||+q_eff)
    __shared__ float pfs[128];     // exp(p/P_SCALE)

    const int tid = (int)threadIdx.x;
    // bijective XCD swizzle: 1024 blocks, 8 XCDs, 128 consecutive l per XCD
    const int l = ((int)blockIdx.x & 7) * 128 + ((int)blockIdx.x >> 3);
    const int b = l >> 5, y0 = (l & 31) * 2;

    if (tid < 128) pfs[tid] = expf(p[tid] * 0.2f);

    // ---- stage 4 input rows (y0-1 .. y0+2) + fused fp32 norm partials
    {
        const int r = tid >> 6;        // staged row 0..3
        const int col = tid & 63;
        const int row = y0 + r - 1;
        unsigned short* dst = &A[(r * 66 + col + 1) * 72];
        float s = 0.f;
        if ((unsigned)row < 64u) {
            const float4* src = reinterpret_cast<const float4*>(
                in + (size_t)b * 262144 + row * 4096 + col * 64);
#pragma unroll
            for (int it = 0; it < 8; ++it) {
                float4 v0 = src[2 * it];
                float4 v1 = src[2 * it + 1];
                s += v0.x * v0.x + v0.y * v0.y + v0.z * v0.z + v0.w * v0.w;
                s += v1.x * v1.x + v1.y * v1.y + v1.z * v1.z + v1.w * v1.w;
                union { float f; unsigned u; } ux, uy, uz, uw;
                uint4 pk;
                ux.f = v0.x; uy.f = v0.y; uz.f = v0.z; uw.f = v0.w;
                pk.x = __builtin_amdgcn_perm(uy.u + 0x8000u, ux.u + 0x8000u, 0x07060302u);
                pk.y = __builtin_amdgcn_perm(uw.u + 0x8000u, uz.u + 0x8000u, 0x07060302u);
                ux.f = v1.x; uy.f = v1.y; uz.f = v1.z; uw.f = v1.w;
                pk.z = __builtin_amdgcn_perm(uy.u + 0x8000u, ux.u + 0x8000u, 0x07060302u);
                pk.w = __builtin_amdgcn_perm(uw.u + 0x8000u, uz.u + 0x8000u, 0x07060302u);
                *reinterpret_cast<uint4*>(dst + it * 8) = pk;
            }
        } else {
            uint4 z; z.x = z.y = z.z = z.w = 0u;
#pragma unroll
            for (int it = 0; it < 8; ++it)
                *reinterpret_cast<uint4*>(dst + it * 8) = z;
        }
        rcsum[tid] = s;
    }
    if (tid < 64) {  // zero border cols 0 and 65, all 4 rows
        const int r = tid >> 4, side = (tid >> 3) & 1, ch = (tid & 7) * 8;
        uint4 z; z.x = z.y = z.z = z.w = 0u;
        *reinterpret_cast<uint4*>(&A[(r * 66 + side * 65) * 72 + ch]) = z;
    }
    __syncthreads();

    // ---- per-pixel 1/(||x||+q_eff) from fp32 partials
    if (tid < 128) {
        const int ry = tid >> 6, x = tid & 63;
        const float qe = expf(q[0] * (-1.0f / 0.3f));
        float s = 0.f;
#pragma unroll
        for (int dy = 0; dy < 3; ++dy) {
            const float* rs = &rcsum[(ry + dy) * 64];
            if (x > 0) s += rs[x - 1];
            s += rs[x];
            if (x < 63) s += rs[x + 1];
        }
        xni[tid] = 1.0f / (sqrtf(fmaxf(s, 1e-12f)) + qe);
    }
    __syncthreads();   // xni/pfs ready -> epilogue needs NO barrier

    // ---- MFMA loop (32x32x16): wave = output-row wm, 64 px x 64 n (n-half
    // wnh) as 2x2 tiles of 32x32. Per step: 4 A ds_reads + 4 B loads + 8 MFMA.
    // A-frag: row = l&31, k = 8*(l>>5)+j. B-frag: col = l&31, same k.
    const int wv = tid >> 6, lane = tid & 63;
    const int ln31 = lane & 31, khi = lane >> 5;   // khi in {0,1}
    const int wm = wv >> 1, wnh = wv & 1;
    f32x16 acc00 = {}, acc01 = {}, acc10 = {}, acc11 = {};
    // B base for this lane: + tn*1024 selects n-tile, + sk*16 selects sub-k
    const unsigned short* wB = wn + (wnh * 64 + ln31) * 32 + khi * 8;

    bf16x8 bc00 = *reinterpret_cast<const bf16x8*>(wB);            // tn0 sk0
    bf16x8 bc01 = *reinterpret_cast<const bf16x8*>(wB + 16);       // tn0 sk1
    bf16x8 bc10 = *reinterpret_cast<const bf16x8*>(wB + 1024);     // tn1 sk0
    bf16x8 bc11 = *reinterpret_cast<const bf16x8*>(wB + 1040);     // tn1 sk1

#pragma unroll
    for (int s = 0; s < 18; ++s) {
        bf16x8 bn00, bn01, bn10, bn11;
        if (s + 1 < 18) {
            const unsigned short* wt = wB + (s + 1) * 4096;
            bn00 = *reinterpret_cast<const bf16x8*>(wt);
            bn01 = *reinterpret_cast<const bf16x8*>(wt + 16);
            bn10 = *reinterpret_cast<const bf16x8*>(wt + 1024);
            bn11 = *reinterpret_cast<const bf16x8*>(wt + 1040);
        }
        const int dy = s / 6, dx = (s >> 1) % 3, kc = s & 1;
        const unsigned short* arow =
            &A[((wm + dy) * 66 + ln31 + dx) * 72 + kc * 32 + khi * 8];
        // tm=0
        {
            bf16x8 a0 = *reinterpret_cast<const bf16x8*>(arow);          // sk0
            bf16x8 a1 = *reinterpret_cast<const bf16x8*>(arow + 16);     // sk1
            acc00 = __builtin_amdgcn_mfma_f32_32x32x16_bf16(a0, bc00, acc00, 0, 0, 0);
            acc01 = __builtin_amdgcn_mfma_f32_32x32x16_bf16(a0, bc10, acc01, 0, 0, 0);
            acc00 = __builtin_amdgcn_mfma_f32_32x32x16_bf16(a1, bc01, acc00, 0, 0, 0);
            acc01 = __builtin_amdgcn_mfma_f32_32x32x16_bf16(a1, bc11, acc01, 0, 0, 0);
        }
        // tm=1 (+32 px cols)
        {
            bf16x8 a0 = *reinterpret_cast<const bf16x8*>(arow + 32 * 72);
            bf16x8 a1 = *reinterpret_cast<const bf16x8*>(arow + 32 * 72 + 16);
            acc10 = __builtin_amdgcn_mfma_f32_32x32x16_bf16(a0, bc00, acc10, 0, 0, 0);
            acc11 = __builtin_amdgcn_mfma_f32_32x32x16_bf16(a0, bc10, acc11, 0, 0, 0);
            acc10 = __builtin_amdgcn_mfma_f32_32x32x16_bf16(a1, bc01, acc10, 0, 0, 0);
            acc11 = __builtin_amdgcn_mfma_f32_32x32x16_bf16(a1, bc11, acc11, 0, 0, 0);
        }
        bc00 = bn00; bc01 = bn01; bc10 = bn10; bc11 = bn11;
    }

    // ---- epilogue (barrier-free): sim = acc*xni; out = sign*(|sim|+eps)^p
    // C/D 32x32: col(n) = lane&31, row(px) = (r&3) + 8*(r>>2) + 4*(lane>>5)
    float* orow = out + ((size_t)(b * 64 + y0 + wm) * 64) * 128;
#pragma unroll
    for (int tm = 0; tm < 2; ++tm) {
#pragma unroll
        for (int tn = 0; tn < 2; ++tn) {
            const f32x16& av = tm == 0 ? (tn == 0 ? acc00 : acc01)
                                       : (tn == 0 ? acc10 : acc11);
            const int n = wnh * 64 + tn * 32 + ln31;
            const float pn = pfs[n];
#pragma unroll
            for (int r = 0; r < 16; ++r) {
                const int px = tm * 32 + (r & 3) + 8 * (r >> 2) + 4 * khi;
                float sim = av[r] * xni[wm * 64 + px];
                float aa = fabsf(sim) + 1e-6f;
                float rr = exp2f(pn * log2f(aa));
                orow[(size_t)px * 128 + n] = copysignf(rr, sim);
            }
        }
    }
}

extern "C" void kernel_launch(void* const* d_in, const int* in_sizes, int n_in,
                              void* d_out, int out_size, void* d_ws, size_t ws_size,
                              hipStream_t stream) {
    (void)in_sizes; (void)n_in; (void)out_size; (void)ws_size;
    const float* in = (const float*)d_in[0];
    const float* w  = (const float*)d_in[1];
    const float* p  = (const float*)d_in[2];
    const float* q  = (const float*)d_in[3];
    float* out = (float*)d_out;
    unsigned short* wn = (unsigned short*)d_ws;  // 18*128*32 bf16 = 147456 B

    prep_w_kernel<<<128, 64, 0, stream>>>(w, wn);
    cossim_main<<<1024, 256, 0, stream>>>(in, wn, p, q, out);
}